// Round 5
// baseline (3706.440 us; speedup 1.0000x reference)
//
#include <hip/hip_runtime.h>
#include <cstdint>
#include <cstddef>

#define HD 4096
#define EE 8
#define LL 8
#define RR 4
#define VV 32000
#define NTOK 2048
#define NKT (HD / 64)   // 64 K-tiles of BK=64
#define T8 8            // tokens per layer block

typedef __attribute__((ext_vector_type(8))) short bf16x8;
typedef __attribute__((ext_vector_type(4))) float f32x4;

static __device__ __forceinline__ unsigned short f2bf(float f) {
    unsigned int u = __builtin_bit_cast(unsigned int, f);
    unsigned int r = (u + 0x7FFFu + ((u >> 16) & 1u)) >> 16;
    return (unsigned short)r;
}

static __device__ __forceinline__ int4 pack_bf16_8(float4 lo, float4 hi) {
    int4 r;
    r.x = (int)((unsigned)f2bf(lo.x) | ((unsigned)f2bf(lo.y) << 16));
    r.y = (int)((unsigned)f2bf(lo.z) | ((unsigned)f2bf(lo.w) << 16));
    r.z = (int)((unsigned)f2bf(hi.x) | ((unsigned)f2bf(hi.y) << 16));
    r.w = (int)((unsigned)f2bf(hi.z) | ((unsigned)f2bf(hi.w) << 16));
    return r;
}

// ---------------------------------------------------------------------------
// Kernel 1: router (double softmax) + 8 fused LoRA layers. (unchanged R4)
// 256 blocks x 512 threads; 8 tokens/block; runs ALONE (R3 L2-thrash lesson).
// ---------------------------------------------------------------------------
__global__ __launch_bounds__(512, 2) void fused_layers(
    const float* __restrict__ h_in,
    const float* __restrict__ router_w,
    const float* __restrict__ router_b,
    const float* __restrict__ expert_B,   // [E][L][R][H]
    const float* __restrict__ expert_A,   // [E][L][H][R]
    const float* __restrict__ deep_B,     // [L][R][H]
    const float* __restrict__ deep_A,     // [L][H][R]
    float* __restrict__ router_logits,
    unsigned short* __restrict__ h_out)
{
    __shared__ float h_lds[T8][HD];       // 128 KB
    __shared__ float zw_lds[T8][32];
    __shared__ float probs_lds[T8][EE];
    __shared__ float psum_lds[T8];
    __shared__ float red[8][T8][4];
    __shared__ float low_lds[T8][4];

    const int tid  = threadIdx.x;
    const int lane = tid & 63;
    const int wv   = tid >> 6;            // 0..7
    const int t0   = blockIdx.x * T8;

    for (int t = 0; t < T8; ++t) {
        const float4* src = (const float4*)(h_in + (size_t)(t0 + t) * HD);
        float4* dst = (float4*)h_lds[t];
        #pragma unroll
        for (int q = 0; q < 2; ++q) dst[tid + q * 512] = src[tid + q * 512];
    }
    __syncthreads();

    {
        float racc[EE];
        #pragma unroll
        for (int e = 0; e < EE; ++e) racc[e] = 0.f;
        const float4* h4 = (const float4*)h_lds[wv];
        for (int k4 = 0; k4 < HD / 256; ++k4) {
            int idx = lane + k4 * 64;
            float4 hv = h4[idx];
            #pragma unroll
            for (int e = 0; e < EE; ++e) {
                float4 w4 = ((const float4*)(router_w + e * HD))[idx];
                racc[e] += w4.x * hv.x + w4.y * hv.y + w4.z * hv.z + w4.w * hv.w;
            }
        }
        #pragma unroll
        for (int e = 0; e < EE; ++e)
            for (int m = 1; m < 64; m <<= 1) racc[e] += __shfl_xor(racc[e], m);
        if (lane == 0) {
            float lg[EE], mx = -1e30f;
            #pragma unroll
            for (int e = 0; e < EE; ++e) { lg[e] = racc[e] + router_b[e]; mx = fmaxf(mx, lg[e]); }
            float s = 0.f;
            #pragma unroll
            for (int e = 0; e < EE; ++e) { lg[e] = expf(lg[e] - mx); s += lg[e]; }
            float inv = 1.f / s;
            float p1[EE], mx2 = -1e30f;
            #pragma unroll
            for (int e = 0; e < EE; ++e) { p1[e] = lg[e] * inv; mx2 = fmaxf(mx2, p1[e]); }
            float s2 = 0.f, q2[EE];
            #pragma unroll
            for (int e = 0; e < EE; ++e) { q2[e] = expf(p1[e] - mx2); s2 += q2[e]; }
            float inv2 = 1.f / s2, ps = 0.f;
            #pragma unroll
            for (int e = 0; e < EE; ++e) {
                float p2 = q2[e] * inv2;
                probs_lds[wv][e] = p2;
                ps += p2;
                router_logits[(size_t)(t0 + wv) * EE + e] = p1[e];
            }
            psum_lds[wv] = ps;
        }
    }
    __syncthreads();

    for (int li = 0; li < LL; ++li) {
        {
            float zacc[4][T8] = {};
            const float4* bp4[4];
            #pragma unroll
            for (int j = 0; j < 4; ++j) {
                int er = wv * 4 + j;
                int e = er >> 2, r = er & 3;
                bp4[j] = (const float4*)(expert_B + (size_t)((e * LL + li) * RR + r) * HD);
            }
            for (int k4 = 0; k4 < HD / 256; ++k4) {
                int idx = lane + k4 * 64;
                float4 hv[T8];
                #pragma unroll
                for (int t = 0; t < T8; ++t) hv[t] = ((const float4*)h_lds[t])[idx];
                #pragma unroll
                for (int j = 0; j < 4; ++j) {
                    float4 w4 = bp4[j][idx];
                    #pragma unroll
                    for (int t = 0; t < T8; ++t)
                        zacc[j][t] += w4.x * hv[t].x + w4.y * hv[t].y +
                                      w4.z * hv[t].z + w4.w * hv[t].w;
                }
            }
            #pragma unroll
            for (int j = 0; j < 4; ++j)
                #pragma unroll
                for (int t = 0; t < T8; ++t) {
                    float v = zacc[j][t];
                    for (int m = 1; m < 64; m <<= 1) v += __shfl_xor(v, m);
                    zacc[j][t] = v;
                }
            if (lane == 0) {
                #pragma unroll
                for (int j = 0; j < 4; ++j) {
                    int er = wv * 4 + j;
                    #pragma unroll
                    for (int t = 0; t < T8; ++t)
                        zw_lds[t][er] = zacc[j][t] * probs_lds[t][er >> 2];
                }
            }
        }
        __syncthreads();

        float dacc[T8][8] = {};
        const int pbase = wv * 512 + lane;
        for (int e = 0; e < EE; ++e) {
            float zwt[T8][4];
            #pragma unroll
            for (int t = 0; t < T8; ++t)
                #pragma unroll
                for (int r = 0; r < RR; ++r) zwt[t][r] = zw_lds[t][e * 4 + r];
            const float4* ap = (const float4*)expert_A + (size_t)(e * LL + li) * HD;
            #pragma unroll
            for (int it = 0; it < 8; ++it) {
                float4 a4 = ap[pbase + it * 64];
                #pragma unroll
                for (int t = 0; t < T8; ++t)
                    dacc[t][it] += zwt[t][0] * a4.x + zwt[t][1] * a4.y +
                                   zwt[t][2] * a4.z + zwt[t][3] * a4.w;
            }
        }

        float lowacc[T8][4] = {};
        float psv[T8];
        #pragma unroll
        for (int t = 0; t < T8; ++t) psv[t] = psum_lds[t];
        const float* dbp = deep_B + (size_t)li * (RR * HD);
        #pragma unroll
        for (int it = 0; it < 8; ++it) {
            int pos = pbase + it * 64;
            float db0 = dbp[pos], db1 = dbp[HD + pos], db2 = dbp[2 * HD + pos], db3 = dbp[3 * HD + pos];
            #pragma unroll
            for (int t = 0; t < T8; ++t) {
                float c = h_lds[t][pos] * psv[t] + dacc[t][it];
                h_lds[t][pos] = c;
                lowacc[t][0] += c * db0; lowacc[t][1] += c * db1;
                lowacc[t][2] += c * db2; lowacc[t][3] += c * db3;
            }
        }
        #pragma unroll
        for (int t = 0; t < T8; ++t)
            #pragma unroll
            for (int r = 0; r < RR; ++r) {
                float v = lowacc[t][r];
                for (int m = 1; m < 64; m <<= 1) v += __shfl_xor(v, m);
                lowacc[t][r] = v;
            }
        if (lane == 0) {
            #pragma unroll
            for (int t = 0; t < T8; ++t)
                #pragma unroll
                for (int r = 0; r < RR; ++r) red[wv][t][r] = lowacc[t][r];
        }
        __syncthreads();
        if (tid < 32) {
            int t = tid >> 2, r = tid & 3;
            float s = 0.f;
            #pragma unroll
            for (int w = 0; w < 8; ++w) s += red[w][t][r];
            low_lds[t][r] = s;
        }
        __syncthreads();

        {
            float lw[T8][4];
            #pragma unroll
            for (int t = 0; t < T8; ++t)
                #pragma unroll
                for (int r = 0; r < RR; ++r) lw[t][r] = low_lds[t][r];
            const float4* dap = (const float4*)deep_A + (size_t)li * HD;
            #pragma unroll
            for (int it = 0; it < 8; ++it) {
                int pos = pbase + it * 64;
                float4 a4 = dap[pos];
                #pragma unroll
                for (int t = 0; t < T8; ++t)
                    h_lds[t][pos] += lw[t][0] * a4.x + lw[t][1] * a4.y +
                                     lw[t][2] * a4.z + lw[t][3] * a4.w;
            }
        }
        __syncthreads();
    }

    for (int t = 0; t < T8; ++t) {
        ushort4* dst = (ushort4*)(h_out + (size_t)(t0 + t) * HD);
        const float4* src = (const float4*)h_lds[t];
        #pragma unroll
        for (int q = 0; q < 2; ++q) {
            int c = tid + q * 512;
            float4 v = src[c];
            ushort4 o;
            o.x = f2bf(v.x); o.y = f2bf(v.y); o.z = f2bf(v.z); o.w = f2bf(v.w);
            dst[c] = o;
        }
    }
}

// ---------------------------------------------------------------------------
// Kernel 2: 256x256 8-phase bf16 GEMM, B read as FP32 + converted in-kernel.
// C[2048][32000] = A_bf16[2048][4096] * (cvt_bf16(Bw32[32000][4096]))^T
//
// A: global_load_lds (unchanged).  B: reg-staged fp32 -> f2bf -> ds_write,
// placing byte-identical data at byte-identical LDS offsets as the old GLD
// path (swizzle embedded in the source decode), so the read side and MFMA
// mapping are untouched.
//
// Per iter kt: P0: ds_read aF-mh0(8)+bF0(4) | GLD A(kt+1) h0+h1 [pin] |
//              load B(kt+2)-h0 regs | bar | MFMA q00 | bar
//              P1: ds_read bF1(4) | load B(kt+2)-h1 regs | bar | MFMA q01 | bar
//              P2: ds_read aF-mh1(8) | cvt+ds_write B-h0 -> buf[cur] | bar | MFMA q11 | bar
//              P3: cvt+ds_write B-h1 | lgkmcnt(0) [tail: +vmcnt(0)] | bar | MFMA q10 | bar
// Hazards: GLD A pinned (sched_barrier) BEFORE B loads, so the compiler's
// exact vmcnt for the P2 cvt also drains A(kt+1) before the P3 publish
// barrier. cur-B region written at P2 only after its last reader (P1) passed
// a barrier; tile kt+2 data read 2 iterations later.
// ---------------------------------------------------------------------------
#define GLD(src, dst) __builtin_amdgcn_global_load_lds( \
    (const __attribute__((address_space(1))) unsigned int*)(src), \
    (__attribute__((address_space(3))) unsigned int*)(dst), 16, 0, 0)

#define STAGE_A(bufv, hh, ktv) do { \
    char* da_ = smem + (bufv) * 65536 + (hh) * 16384 + wv * 1024; \
    GLD(pA[0] + (size_t)(hh) * (128ull * HD * 2) + (size_t)(ktv) * 128, da_); \
    GLD(pA[1] + (size_t)(hh) * (128ull * HD * 2) + (size_t)(ktv) * 128, da_ + 8192); \
} while (0)

#define LB_LOAD(hh, ktv, d0, d1, d2, d3) do { \
    const char* s0_ = pB32[0] + (size_t)(hh) * 2097152ull + (size_t)(ktv) * 256; \
    const char* s1_ = pB32[1] + (size_t)(hh) * 2097152ull + (size_t)(ktv) * 256; \
    d0 = *(const float4*)(s0_);      d1 = *(const float4*)(s0_ + 16); \
    d2 = *(const float4*)(s1_);      d3 = *(const float4*)(s1_ + 16); \
} while (0)

#define B_WRITE(bufv, hh, d0, d1, d2, d3) do { \
    int4 w0_ = pack_bf16_8(d0, d1); \
    int4 w1_ = pack_bf16_8(d2, d3); \
    char* bb_ = smem + (bufv) * 65536 + 32768 + (hh) * 16384 + tid * 16; \
    *(int4*)(bb_)        = w0_; \
    *(int4*)(bb_ + 8192) = w1_; \
} while (0)

#define LDSREAD(off) (*(const bf16x8*)(smem + (off)))

__global__ __launch_bounds__(512, 2) void lm_gemm256(
    const unsigned short* __restrict__ A,   // bf16 [2048][4096]
    const float* __restrict__ Bw32,         // fp32 [32000][4096]
    float* __restrict__ C)                  // [2048][32000]
{
    __shared__ __attribute__((aligned(128))) char smem[131072];

    const int bid = blockIdx.x;
    const int swz = (bid & 7) * 125 + (bid >> 3);
    const int bm = swz & 7;
    const int bn = swz >> 3;

    const int tid  = threadIdx.x;
    const int lane = tid & 63;
    const int wv   = tid >> 6;
    const int wr   = wv >> 2;
    const int wc   = wv & 3;

    // staging address decode (identical logical mapping to the old GLD path)
    const char* pA[2];
    const char* pB32[2];
    #pragma unroll
    for (int q = 0; q < 2; ++q) {
        int off = (q * 512 + tid) * 16;
        int p = off ^ (((off >> 9) & 1) << 5);
        int st = p >> 10;
        int r  = (st >> 1) * 16 + ((p >> 6) & 15);
        int cb = (st & 1) * 64 + (p & 63);
        pA[q]   = (const char*)(A + (size_t)(bm * 256 + r) * HD) + cb;
        pB32[q] = (const char*)Bw32 + (size_t)(bn * 256 + r) * HD * 4 + cb * 2;
    }

    const int xlane = ((lane >> 3) & 1) << 5;
    const int abase = ((wr * 8) << 11) + ((lane & 15) << 6) + ((lane >> 4) << 4);
    const int bbase = 32768 + ((wc * 4) << 11) + ((lane & 15) << 6) + ((lane >> 4) << 4);

    f32x4 acc[8][4] = {};
    bf16x8 aF[4][2], bF0[2][2], bF1[2][2];
    float4 rb0, rb1, rb2, rb3, rc0, rc1, rc2, rc3;   // B staging regs (h0 / h1)

    // ---- prologue: B(0)->buf0, B(1)->buf1 (reg+cvt), A(0)->buf0 (GLD)
    LB_LOAD(0, 0, rb0, rb1, rb2, rb3);
    LB_LOAD(1, 0, rc0, rc1, rc2, rc3);
    STAGE_A(0, 0, 0);
    STAGE_A(0, 1, 0);
    B_WRITE(0, 0, rb0, rb1, rb2, rb3);
    B_WRITE(0, 1, rc0, rc1, rc2, rc3);
    LB_LOAD(0, 1, rb0, rb1, rb2, rb3);
    LB_LOAD(1, 1, rc0, rc1, rc2, rc3);
    B_WRITE(1, 0, rb0, rb1, rb2, rb3);
    B_WRITE(1, 1, rc0, rc1, rc2, rc3);
    asm volatile("s_waitcnt vmcnt(0) lgkmcnt(0)" ::: "memory");
    __builtin_amdgcn_s_barrier();
    __builtin_amdgcn_sched_barrier(0);

    #pragma unroll 2
    for (int kt = 0; kt < NKT; ++kt) {
        const int cur = kt & 1;
        const int oth = cur ^ 1;
        const int cb0 = cur << 16;

        // ---------------- PHASE 0 : (mh0, nh0)
        #pragma unroll
        for (int i = 0; i < 4; ++i)
            #pragma unroll
            for (int ks = 0; ks < 2; ++ks)
                aF[i][ks] = LDSREAD(cb0 + ((abase + (i << 11) + (ks << 10)) ^ xlane));
        #pragma unroll
        for (int n = 0; n < 2; ++n)
            #pragma unroll
            for (int ks = 0; ks < 2; ++ks)
                bF0[n][ks] = LDSREAD(cb0 + ((bbase + (n << 11) + (ks << 10)) ^ xlane));
        if (kt + 1 < NKT) {
            STAGE_A(oth, 0, kt + 1);
            STAGE_A(oth, 1, kt + 1);
        }
        __builtin_amdgcn_sched_barrier(0);   // pin: GLD A older than B loads
        if (kt + 2 < NKT) LB_LOAD(0, kt + 2, rb0, rb1, rb2, rb3);
        __builtin_amdgcn_s_barrier();
        __builtin_amdgcn_sched_barrier(0);
        __builtin_amdgcn_s_setprio(1);
        #pragma unroll
        for (int ks = 0; ks < 2; ++ks)
            #pragma unroll
            for (int i = 0; i < 4; ++i)
                #pragma unroll
                for (int n = 0; n < 2; ++n)
                    acc[i][n] = __builtin_amdgcn_mfma_f32_16x16x32_bf16(
                        aF[i][ks], bF0[n][ks], acc[i][n], 0, 0, 0);
        __builtin_amdgcn_s_setprio(0);
        __builtin_amdgcn_s_barrier();
        __builtin_amdgcn_sched_barrier(0);

        // ---------------- PHASE 1 : (mh0, nh1)
        #pragma unroll
        for (int n = 0; n < 2; ++n)
            #pragma unroll
            for (int ks = 0; ks < 2; ++ks)
                bF1[n][ks] = LDSREAD(cb0 + ((bbase + ((n + 2) << 11) + (ks << 10)) ^ xlane));
        if (kt + 2 < NKT) LB_LOAD(1, kt + 2, rc0, rc1, rc2, rc3);
        __builtin_amdgcn_s_barrier();
        __builtin_amdgcn_sched_barrier(0);
        __builtin_amdgcn_s_setprio(1);
        #pragma unroll
        for (int ks = 0; ks < 2; ++ks)
            #pragma unroll
            for (int i = 0; i < 4; ++i)
                #pragma unroll
                for (int n = 0; n < 2; ++n)
                    acc[i][n + 2] = __builtin_amdgcn_mfma_f32_16x16x32_bf16(
                        aF[i][ks], bF1[n][ks], acc[i][n + 2], 0, 0, 0);
        __builtin_amdgcn_s_setprio(0);
        __builtin_amdgcn_s_barrier();
        __builtin_amdgcn_sched_barrier(0);

        // ---------------- PHASE 2 : (mh1, nh1)
        #pragma unroll
        for (int i = 0; i < 4; ++i)
            #pragma unroll
            for (int ks = 0; ks < 2; ++ks)
                aF[i][ks] = LDSREAD(cb0 + ((abase + ((i + 4) << 11) + (ks << 10)) ^ xlane));
        if (kt + 2 < NKT) B_WRITE(cur, 0, rb0, rb1, rb2, rb3);  // cvt waits drain A(kt+1) too
        __builtin_amdgcn_s_barrier();
        __builtin_amdgcn_sched_barrier(0);
        __builtin_amdgcn_s_setprio(1);
        #pragma unroll
        for (int ks = 0; ks < 2; ++ks)
            #pragma unroll
            for (int i = 0; i < 4; ++i)
                #pragma unroll
                for (int n = 0; n < 2; ++n)
                    acc[i + 4][n + 2] = __builtin_amdgcn_mfma_f32_16x16x32_bf16(
                        aF[i][ks], bF1[n][ks], acc[i + 4][n + 2], 0, 0, 0);
        __builtin_amdgcn_s_setprio(0);
        __builtin_amdgcn_s_barrier();
        __builtin_amdgcn_sched_barrier(0);

        // ---------------- PHASE 3 : (mh1, nh0)
        if (kt + 2 < NKT) B_WRITE(cur, 1, rc0, rc1, rc2, rc3);
        if (kt >= NKT - 2)
            asm volatile("s_waitcnt vmcnt(0) lgkmcnt(0)" ::: "memory");
        else
            asm volatile("s_waitcnt lgkmcnt(0)" ::: "memory");
        __builtin_amdgcn_s_barrier();
        __builtin_amdgcn_sched_barrier(0);
        __builtin_amdgcn_s_setprio(1);
        #pragma unroll
        for (int ks = 0; ks < 2; ++ks)
            #pragma unroll
            for (int i = 0; i < 4; ++i)
                #pragma unroll
                for (int n = 0; n < 2; ++n)
                    acc[i + 4][n] = __builtin_amdgcn_mfma_f32_16x16x32_bf16(
                        aF[i][ks], bF0[n][ks], acc[i + 4][n], 0, 0, 0);
        __builtin_amdgcn_s_setprio(0);
        __builtin_amdgcn_s_barrier();
        __builtin_amdgcn_sched_barrier(0);
    }

    // epilogue: D frag row=(lane>>4)*4+j (m), col=lane&15 (n)
    const int crow0 = bm * 256 + wr * 128 + ((lane >> 4) << 2);
    const int ccol0 = bn * 256 + wc * 64 + (lane & 15);
    #pragma unroll
    for (int fm = 0; fm < 8; ++fm)
        #pragma unroll
        for (int fn = 0; fn < 4; ++fn) {
            int row = crow0 + fm * 16;
            int col = ccol0 + fn * 16;
            #pragma unroll
            for (int j = 0; j < 4; ++j)
                C[(size_t)(row + j) * VV + col] = acc[fm][fn][j];
        }
}

// ---------------------------------------------------------------------------
extern "C" void kernel_launch(void* const* d_in, const int* in_sizes, int n_in,
                              void* d_out, int out_size, void* d_ws, size_t ws_size,
                              hipStream_t stream) {
    const float* h_in      = (const float*)d_in[0];
    const float* router_w  = (const float*)d_in[1];
    const float* router_b  = (const float*)d_in[2];
    const float* expert_B  = (const float*)d_in[3];
    const float* expert_A  = (const float*)d_in[4];
    const float* deep_B    = (const float*)d_in[5];
    const float* deep_A    = (const float*)d_in[6];
    const float* lm_head_w = (const float*)d_in[7];

    float* out = (float*)d_out;
    float* router_logits_out = out + (size_t)NTOK * VV;

    unsigned short* h_bf = (unsigned short*)d_ws;   // bf16 h, 16 MB

    fused_layers<<<dim3(NTOK / T8), dim3(512), 0, stream>>>(
        h_in, router_w, router_b, expert_B, expert_A, deep_B, deep_A,
        router_logits_out, h_bf);

    lm_gemm256<<<dim3((NTOK / 256) * (VV / 256)), dim3(512), 0, stream>>>(
        h_bf, lm_head_w, out);
}

// Round 6
// 1327.426 us; speedup vs baseline: 2.7922x; 2.7922x over previous
//
#include <hip/hip_runtime.h>
#include <cstdint>
#include <cstddef>

#define HD 4096
#define EE 8
#define LL 8
#define RR 4
#define VV 32000
#define NTOK 2048
#define NKT (HD / 64)   // 64 K-tiles of BK=64
#define T8 8            // tokens per layer block
#define SCR 131072      // scratch fp32 staging base in smem

typedef __attribute__((ext_vector_type(8))) short bf16x8;
typedef __attribute__((ext_vector_type(4))) float f32x4;

static __device__ __forceinline__ unsigned short f2bf(float f) {
    unsigned int u = __builtin_bit_cast(unsigned int, f);
    unsigned int r = (u + 0x7FFFu + ((u >> 16) & 1u)) >> 16;
    return (unsigned short)r;
}

static __device__ __forceinline__ int4 pack_bf16_8(float4 lo, float4 hi) {
    int4 r;
    r.x = (int)((unsigned)f2bf(lo.x) | ((unsigned)f2bf(lo.y) << 16));
    r.y = (int)((unsigned)f2bf(lo.z) | ((unsigned)f2bf(lo.w) << 16));
    r.z = (int)((unsigned)f2bf(hi.x) | ((unsigned)f2bf(hi.y) << 16));
    r.w = (int)((unsigned)f2bf(hi.z) | ((unsigned)f2bf(hi.w) << 16));
    return r;
}

// ---------------------------------------------------------------------------
// Kernel 1: router (double softmax) + 8 fused LoRA layers. (unchanged R4)
// ---------------------------------------------------------------------------
__global__ __launch_bounds__(512, 2) void fused_layers(
    const float* __restrict__ h_in,
    const float* __restrict__ router_w,
    const float* __restrict__ router_b,
    const float* __restrict__ expert_B,   // [E][L][R][H]
    const float* __restrict__ expert_A,   // [E][L][H][R]
    const float* __restrict__ deep_B,     // [L][R][H]
    const float* __restrict__ deep_A,     // [L][H][R]
    float* __restrict__ router_logits,
    unsigned short* __restrict__ h_out)
{
    __shared__ float h_lds[T8][HD];       // 128 KB
    __shared__ float zw_lds[T8][32];
    __shared__ float probs_lds[T8][EE];
    __shared__ float psum_lds[T8];
    __shared__ float red[8][T8][4];
    __shared__ float low_lds[T8][4];

    const int tid  = threadIdx.x;
    const int lane = tid & 63;
    const int wv   = tid >> 6;            // 0..7
    const int t0   = blockIdx.x * T8;

    for (int t = 0; t < T8; ++t) {
        const float4* src = (const float4*)(h_in + (size_t)(t0 + t) * HD);
        float4* dst = (float4*)h_lds[t];
        #pragma unroll
        for (int q = 0; q < 2; ++q) dst[tid + q * 512] = src[tid + q * 512];
    }
    __syncthreads();

    {
        float racc[EE];
        #pragma unroll
        for (int e = 0; e < EE; ++e) racc[e] = 0.f;
        const float4* h4 = (const float4*)h_lds[wv];
        for (int k4 = 0; k4 < HD / 256; ++k4) {
            int idx = lane + k4 * 64;
            float4 hv = h4[idx];
            #pragma unroll
            for (int e = 0; e < EE; ++e) {
                float4 w4 = ((const float4*)(router_w + e * HD))[idx];
                racc[e] += w4.x * hv.x + w4.y * hv.y + w4.z * hv.z + w4.w * hv.w;
            }
        }
        #pragma unroll
        for (int e = 0; e < EE; ++e)
            for (int m = 1; m < 64; m <<= 1) racc[e] += __shfl_xor(racc[e], m);
        if (lane == 0) {
            float lg[EE], mx = -1e30f;
            #pragma unroll
            for (int e = 0; e < EE; ++e) { lg[e] = racc[e] + router_b[e]; mx = fmaxf(mx, lg[e]); }
            float s = 0.f;
            #pragma unroll
            for (int e = 0; e < EE; ++e) { lg[e] = expf(lg[e] - mx); s += lg[e]; }
            float inv = 1.f / s;
            float p1[EE], mx2 = -1e30f;
            #pragma unroll
            for (int e = 0; e < EE; ++e) { p1[e] = lg[e] * inv; mx2 = fmaxf(mx2, p1[e]); }
            float s2 = 0.f, q2[EE];
            #pragma unroll
            for (int e = 0; e < EE; ++e) { q2[e] = expf(p1[e] - mx2); s2 += q2[e]; }
            float inv2 = 1.f / s2, ps = 0.f;
            #pragma unroll
            for (int e = 0; e < EE; ++e) {
                float p2 = q2[e] * inv2;
                probs_lds[wv][e] = p2;
                ps += p2;
                router_logits[(size_t)(t0 + wv) * EE + e] = p1[e];
            }
            psum_lds[wv] = ps;
        }
    }
    __syncthreads();

    for (int li = 0; li < LL; ++li) {
        {
            float zacc[4][T8] = {};
            const float4* bp4[4];
            #pragma unroll
            for (int j = 0; j < 4; ++j) {
                int er = wv * 4 + j;
                int e = er >> 2, r = er & 3;
                bp4[j] = (const float4*)(expert_B + (size_t)((e * LL + li) * RR + r) * HD);
            }
            for (int k4 = 0; k4 < HD / 256; ++k4) {
                int idx = lane + k4 * 64;
                float4 hv[T8];
                #pragma unroll
                for (int t = 0; t < T8; ++t) hv[t] = ((const float4*)h_lds[t])[idx];
                #pragma unroll
                for (int j = 0; j < 4; ++j) {
                    float4 w4 = bp4[j][idx];
                    #pragma unroll
                    for (int t = 0; t < T8; ++t)
                        zacc[j][t] += w4.x * hv[t].x + w4.y * hv[t].y +
                                      w4.z * hv[t].z + w4.w * hv[t].w;
                }
            }
            #pragma unroll
            for (int j = 0; j < 4; ++j)
                #pragma unroll
                for (int t = 0; t < T8; ++t) {
                    float v = zacc[j][t];
                    for (int m = 1; m < 64; m <<= 1) v += __shfl_xor(v, m);
                    zacc[j][t] = v;
                }
            if (lane == 0) {
                #pragma unroll
                for (int j = 0; j < 4; ++j) {
                    int er = wv * 4 + j;
                    #pragma unroll
                    for (int t = 0; t < T8; ++t)
                        zw_lds[t][er] = zacc[j][t] * probs_lds[t][er >> 2];
                }
            }
        }
        __syncthreads();

        float dacc[T8][8] = {};
        const int pbase = wv * 512 + lane;
        for (int e = 0; e < EE; ++e) {
            float zwt[T8][4];
            #pragma unroll
            for (int t = 0; t < T8; ++t)
                #pragma unroll
                for (int r = 0; r < RR; ++r) zwt[t][r] = zw_lds[t][e * 4 + r];
            const float4* ap = (const float4*)expert_A + (size_t)(e * LL + li) * HD;
            #pragma unroll
            for (int it = 0; it < 8; ++it) {
                float4 a4 = ap[pbase + it * 64];
                #pragma unroll
                for (int t = 0; t < T8; ++t)
                    dacc[t][it] += zwt[t][0] * a4.x + zwt[t][1] * a4.y +
                                   zwt[t][2] * a4.z + zwt[t][3] * a4.w;
            }
        }

        float lowacc[T8][4] = {};
        float psv[T8];
        #pragma unroll
        for (int t = 0; t < T8; ++t) psv[t] = psum_lds[t];
        const float* dbp = deep_B + (size_t)li * (RR * HD);
        #pragma unroll
        for (int it = 0; it < 8; ++it) {
            int pos = pbase + it * 64;
            float db0 = dbp[pos], db1 = dbp[HD + pos], db2 = dbp[2 * HD + pos], db3 = dbp[3 * HD + pos];
            #pragma unroll
            for (int t = 0; t < T8; ++t) {
                float c = h_lds[t][pos] * psv[t] + dacc[t][it];
                h_lds[t][pos] = c;
                lowacc[t][0] += c * db0; lowacc[t][1] += c * db1;
                lowacc[t][2] += c * db2; lowacc[t][3] += c * db3;
            }
        }
        #pragma unroll
        for (int t = 0; t < T8; ++t)
            #pragma unroll
            for (int r = 0; r < RR; ++r) {
                float v = lowacc[t][r];
                for (int m = 1; m < 64; m <<= 1) v += __shfl_xor(v, m);
                lowacc[t][r] = v;
            }
        if (lane == 0) {
            #pragma unroll
            for (int t = 0; t < T8; ++t)
                #pragma unroll
                for (int r = 0; r < RR; ++r) red[wv][t][r] = lowacc[t][r];
        }
        __syncthreads();
        if (tid < 32) {
            int t = tid >> 2, r = tid & 3;
            float s = 0.f;
            #pragma unroll
            for (int w = 0; w < 8; ++w) s += red[w][t][r];
            low_lds[t][r] = s;
        }
        __syncthreads();

        {
            float lw[T8][4];
            #pragma unroll
            for (int t = 0; t < T8; ++t)
                #pragma unroll
                for (int r = 0; r < RR; ++r) lw[t][r] = low_lds[t][r];
            const float4* dap = (const float4*)deep_A + (size_t)li * HD;
            #pragma unroll
            for (int it = 0; it < 8; ++it) {
                int pos = pbase + it * 64;
                float4 a4 = dap[pos];
                #pragma unroll
                for (int t = 0; t < T8; ++t)
                    h_lds[t][pos] += lw[t][0] * a4.x + lw[t][1] * a4.y +
                                     lw[t][2] * a4.z + lw[t][3] * a4.w;
            }
        }
        __syncthreads();
    }

    for (int t = 0; t < T8; ++t) {
        ushort4* dst = (ushort4*)(h_out + (size_t)(t0 + t) * HD);
        const float4* src = (const float4*)h_lds[t];
        #pragma unroll
        for (int q = 0; q < 2; ++q) {
            int c = tid + q * 512;
            float4 v = src[c];
            ushort4 o;
            o.x = f2bf(v.x); o.y = f2bf(v.y); o.z = f2bf(v.z); o.w = f2bf(v.w);
            dst[c] = o;
        }
    }
}

// ---------------------------------------------------------------------------
// Kernel 2: 256x256 8-phase bf16 GEMM; B read as fp32 and converted to bf16
// VIA LDS SCRATCH (no loop-carried staging registers -> no spill).
//
// LDS (160 KB): buf0 [A 32K | B 32K] @0, buf1 @65536, scratch 32K @131072
//   (two 16 KB slots; slot = 2 GLD parts of one 8 KB-bf16 quarter).
// Quarter pipeline: tile T's quarters q0..q3 (hh=qq pairs) are GLD'd (fp32)
// at iter T-2 phases P0..P3 (slot 0,1,0,1) and PROCESSED (ds_read scratch ->
// f2bf -> ds_write to T's parity buffer) two phases later:
//   q0 -> (T-2)P2 [cur], q1 -> (T-2)P3 [cur], q2 -> (T-1)P0 [oth],
//   q3 -> (T-1)P1 [oth].  Process slot X, then GLD into X after the barrier.
// vmcnt ledger (A(4)@P0 pre-barrier, +2 B-GLD/phase post-barrier):
//   gates P0:2, P1:6, P2:2, P3:2; tail kt==NKT-2: P1:4, P2:0 (drain A).
// Writes published by lgkmcnt(0) before each phase barrier.
// ---------------------------------------------------------------------------
#define GLD(src, dst) __builtin_amdgcn_global_load_lds( \
    (const __attribute__((address_space(1))) unsigned int*)(src), \
    (__attribute__((address_space(3))) unsigned int*)(dst), 16, 0, 0)

#define STAGE_A(bufv, hh, ktv) do { \
    char* da_ = smem + (bufv) * 65536 + (hh) * 16384 + wv * 1024; \
    GLD(pA[0] + (size_t)(hh) * (128ull * HD * 2) + (size_t)(ktv) * 128, da_); \
    GLD(pA[1] + (size_t)(hh) * (128ull * HD * 2) + (size_t)(ktv) * 128, da_ + 8192); \
} while (0)

#define GLDQ(ktv, hh, qq, slot) do { \
    char* dq_ = smem + SCR + (slot) * 16384 + wv * 1024; \
    GLD(pB32[qq] + (size_t)(hh) * 2097152ull + (size_t)(ktv) * 256, dq_); \
    GLD(pB32[qq] + (size_t)(hh) * 2097152ull + (size_t)(ktv) * 256 + 16, dq_ + 8192); \
} while (0)

#define PROCQ(tb, hh, qq, slot) do { \
    float4 f0_ = *(const float4*)(smem + SCR + (slot) * 16384 + tid * 16); \
    float4 f1_ = *(const float4*)(smem + SCR + (slot) * 16384 + 8192 + tid * 16); \
    *(int4*)(smem + (tb) * 65536 + 32768 + (hh) * 16384 + (qq) * 8192 + tid * 16) = \
        pack_bf16_8(f0_, f1_); \
} while (0)

#define LDSREAD(off) (*(const bf16x8*)(smem + (off)))

__global__ __launch_bounds__(512, 2) void lm_gemm256(
    const unsigned short* __restrict__ A,   // bf16 [2048][4096]
    const float* __restrict__ Bw32,         // fp32 [32000][4096]
    float* __restrict__ C)                  // [2048][32000]
{
    __shared__ __attribute__((aligned(128))) char smem[163840];

    const int bid = blockIdx.x;
    const int swz = (bid & 7) * 125 + (bid >> 3);
    const int bm = swz & 7;
    const int bn = swz >> 3;

    const int tid  = threadIdx.x;
    const int lane = tid & 63;
    const int wv   = tid >> 6;
    const int wr   = wv >> 2;
    const int wc   = wv & 3;

    // per-thread staging decode (inverse swizzle baked into global source)
    const char* pA[2];
    const char* pB32[2];
    #pragma unroll
    for (int q = 0; q < 2; ++q) {
        int off = (q * 512 + tid) * 16;
        int p = off ^ (((off >> 9) & 1) << 5);
        int st = p >> 10;
        int r  = (st >> 1) * 16 + ((p >> 6) & 15);
        int cb = (st & 1) * 64 + (p & 63);
        pA[q]   = (const char*)(A + (size_t)(bm * 256 + r) * HD) + cb;
        pB32[q] = (const char*)Bw32 + (size_t)(bn * 256 + r) * HD * 4 + cb * 2;
    }

    const int xlane = ((lane >> 3) & 1) << 5;
    const int abase = ((wr * 8) << 11) + ((lane & 15) << 6) + ((lane >> 4) << 4);
    const int bbase = 32768 + ((wc * 4) << 11) + ((lane & 15) << 6) + ((lane >> 4) << 4);

    f32x4 acc[8][4] = {};
    bf16x8 aF[4][2], bF0[2][2], bF1[2][2];

    // ---- prologue ----
    // tile0 B (all 4 quarters) + tile1 B (hh=0 quarters) via direct reg cvt
    #pragma unroll
    for (int p = 0; p < 4; ++p) {
        const int hh = p >> 1, qq = p & 1;
        float4 f0 = *(const float4*)(pB32[qq] + (size_t)hh * 2097152ull);
        float4 f1 = *(const float4*)(pB32[qq] + (size_t)hh * 2097152ull + 16);
        *(int4*)(smem + 32768 + hh * 16384 + qq * 8192 + tid * 16) = pack_bf16_8(f0, f1);
    }
    #pragma unroll
    for (int qq = 0; qq < 2; ++qq) {
        float4 f0 = *(const float4*)(pB32[qq] + 256);
        float4 f1 = *(const float4*)(pB32[qq] + 256 + 16);
        *(int4*)(smem + 65536 + 32768 + qq * 8192 + tid * 16) = pack_bf16_8(f0, f1);
    }
    STAGE_A(0, 0, 0);
    STAGE_A(0, 1, 0);
    GLDQ(1, 1, 0, 0);     // tile1 q2 -> slot0
    GLDQ(1, 1, 1, 1);     // tile1 q3 -> slot1
    asm volatile("s_waitcnt vmcnt(4) lgkmcnt(0)" ::: "memory");  // drain A0; B-GLDs in flight
    __builtin_amdgcn_s_barrier();
    __builtin_amdgcn_sched_barrier(0);

    #pragma unroll 2
    for (int kt = 0; kt < NKT; ++kt) {
        const int cur = kt & 1;
        const int oth = cur ^ 1;
        const int cb0 = cur << 16;

        // ---------------- PHASE 0 : (mh0, nh0)
        #pragma unroll
        for (int i = 0; i < 4; ++i)
            #pragma unroll
            for (int ks = 0; ks < 2; ++ks)
                aF[i][ks] = LDSREAD(cb0 + ((abase + (i << 11) + (ks << 10)) ^ xlane));
        #pragma unroll
        for (int n = 0; n < 2; ++n)
            #pragma unroll
            for (int ks = 0; ks < 2; ++ks)
                bF0[n][ks] = LDSREAD(cb0 + ((bbase + (n << 11) + (ks << 10)) ^ xlane));
        if (kt + 1 < NKT) {
            asm volatile("s_waitcnt vmcnt(2)" ::: "memory");
            PROCQ(oth, 1, 0, 0);                   // tile kt+1 q2
            STAGE_A(oth, 0, kt + 1);
            STAGE_A(oth, 1, kt + 1);
        }
        asm volatile("s_waitcnt lgkmcnt(0)" ::: "memory");
        __builtin_amdgcn_s_barrier();
        __builtin_amdgcn_sched_barrier(0);
        if (kt + 2 < NKT) GLDQ(kt + 2, 0, 0, 0);   // q0 -> slot0
        __builtin_amdgcn_s_setprio(1);
        #pragma unroll
        for (int ks = 0; ks < 2; ++ks)
            #pragma unroll
            for (int i = 0; i < 4; ++i)
                #pragma unroll
                for (int n = 0; n < 2; ++n)
                    acc[i][n] = __builtin_amdgcn_mfma_f32_16x16x32_bf16(
                        aF[i][ks], bF0[n][ks], acc[i][n], 0, 0, 0);
        __builtin_amdgcn_s_setprio(0);
        __builtin_amdgcn_s_barrier();
        __builtin_amdgcn_sched_barrier(0);

        // ---------------- PHASE 1 : (mh0, nh1)
        #pragma unroll
        for (int n = 0; n < 2; ++n)
            #pragma unroll
            for (int ks = 0; ks < 2; ++ks)
                bF1[n][ks] = LDSREAD(cb0 + ((bbase + ((n + 2) << 11) + (ks << 10)) ^ xlane));
        if (kt + 1 < NKT) {
            if (kt == NKT - 2)
                asm volatile("s_waitcnt vmcnt(4)" ::: "memory");
            else
                asm volatile("s_waitcnt vmcnt(6)" ::: "memory");
            PROCQ(oth, 1, 1, 1);                   // tile kt+1 q3
        }
        asm volatile("s_waitcnt lgkmcnt(0)" ::: "memory");
        __builtin_amdgcn_s_barrier();
        __builtin_amdgcn_sched_barrier(0);
        if (kt + 2 < NKT) GLDQ(kt + 2, 0, 1, 1);   // q1 -> slot1
        __builtin_amdgcn_s_setprio(1);
        #pragma unroll
        for (int ks = 0; ks < 2; ++ks)
            #pragma unroll
            for (int i = 0; i < 4; ++i)
                #pragma unroll
                for (int n = 0; n < 2; ++n)
                    acc[i][n + 2] = __builtin_amdgcn_mfma_f32_16x16x32_bf16(
                        aF[i][ks], bF1[n][ks], acc[i][n + 2], 0, 0, 0);
        __builtin_amdgcn_s_setprio(0);
        __builtin_amdgcn_s_barrier();
        __builtin_amdgcn_sched_barrier(0);

        // ---------------- PHASE 2 : (mh1, nh1)
        #pragma unroll
        for (int i = 0; i < 4; ++i)
            #pragma unroll
            for (int ks = 0; ks < 2; ++ks)
                aF[i][ks] = LDSREAD(cb0 + ((abase + ((i + 4) << 11) + (ks << 10)) ^ xlane));
        if (kt + 2 < NKT) {
            asm volatile("s_waitcnt vmcnt(2)" ::: "memory");
            PROCQ(cur, 0, 0, 0);                   // tile kt+2 q0
        } else {
            asm volatile("s_waitcnt vmcnt(0)" ::: "memory");  // tail: drain A
        }
        asm volatile("s_waitcnt lgkmcnt(0)" ::: "memory");
        __builtin_amdgcn_s_barrier();
        __builtin_amdgcn_sched_barrier(0);
        if (kt + 2 < NKT) GLDQ(kt + 2, 1, 0, 0);   // q2 -> slot0
        __builtin_amdgcn_s_setprio(1);
        #pragma unroll
        for (int ks = 0; ks < 2; ++ks)
            #pragma unroll
            for (int i = 0; i < 4; ++i)
                #pragma unroll
                for (int n = 0; n < 2; ++n)
                    acc[i + 4][n + 2] = __builtin_amdgcn_mfma_f32_16x16x32_bf16(
                        aF[i][ks], bF1[n][ks], acc[i + 4][n + 2], 0, 0, 0);
        __builtin_amdgcn_s_setprio(0);
        __builtin_amdgcn_s_barrier();
        __builtin_amdgcn_sched_barrier(0);

        // ---------------- PHASE 3 : (mh1, nh0)  (bF0 held from P0)
        if (kt + 2 < NKT) {
            asm volatile("s_waitcnt vmcnt(2)" ::: "memory");
            PROCQ(cur, 0, 1, 1);                   // tile kt+2 q1
        }
        asm volatile("s_waitcnt lgkmcnt(0)" ::: "memory");
        __builtin_amdgcn_s_barrier();
        __builtin_amdgcn_sched_barrier(0);
        if (kt + 2 < NKT) GLDQ(kt + 2, 1, 1, 1);   // q3 -> slot1
        __builtin_amdgcn_s_setprio(1);
        #pragma unroll
        for (int ks = 0; ks < 2; ++ks)
            #pragma unroll
            for (int i = 0; i < 4; ++i)
                #pragma unroll
                for (int n = 0; n < 2; ++n)
                    acc[i + 4][n] = __builtin_amdgcn_mfma_f32_16x16x32_bf16(
                        aF[i][ks], bF0[n][ks], acc[i + 4][n], 0, 0, 0);
        __builtin_amdgcn_s_setprio(0);
        __builtin_amdgcn_s_barrier();
        __builtin_amdgcn_sched_barrier(0);
    }

    // epilogue: D frag row=(lane>>4)*4+j (m), col=lane&15 (n)
    const int crow0 = bm * 256 + wr * 128 + ((lane >> 4) << 2);
    const int ccol0 = bn * 256 + wc * 64 + (lane & 15);
    #pragma unroll
    for (int fm = 0; fm < 8; ++fm)
        #pragma unroll
        for (int fn = 0; fn < 4; ++fn) {
            int row = crow0 + fm * 16;
            int col = ccol0 + fn * 16;
            #pragma unroll
            for (int j = 0; j < 4; ++j)
                C[(size_t)(row + j) * VV + col] = acc[fm][fn][j];
        }
}

// ---------------------------------------------------------------------------
extern "C" void kernel_launch(void* const* d_in, const int* in_sizes, int n_in,
                              void* d_out, int out_size, void* d_ws, size_t ws_size,
                              hipStream_t stream) {
    const float* h_in      = (const float*)d_in[0];
    const float* router_w  = (const float*)d_in[1];
    const float* router_b  = (const float*)d_in[2];
    const float* expert_B  = (const float*)d_in[3];
    const float* expert_A  = (const float*)d_in[4];
    const float* deep_B    = (const float*)d_in[5];
    const float* deep_A    = (const float*)d_in[6];
    const float* lm_head_w = (const float*)d_in[7];

    float* out = (float*)d_out;
    float* router_logits_out = out + (size_t)NTOK * VV;

    unsigned short* h_bf = (unsigned short*)d_ws;   // bf16 h, 16 MB

    fused_layers<<<dim3(NTOK / T8), dim3(512), 0, stream>>>(
        h_in, router_w, router_b, expert_B, expert_A, deep_B, deep_A,
        router_logits_out, h_bf);

    lm_gemm256<<<dim3((NTOK / 256) * (VV / 256)), dim3(512), 0, stream>>>(
        h_bf, lm_head_w, out);
}

// Round 8
// 908.282 us; speedup vs baseline: 4.0807x; 1.4615x over previous
//
#include <hip/hip_runtime.h>
#include <cstdint>
#include <cstddef>

#define HD 4096
#define EE 8
#define LL 8
#define RR 4
#define VV 32000
#define NTOK 2048
#define NKT (HD / 64)   // 64 K-tiles of BK=64
#define T8 8            // tokens per layer block

typedef __attribute__((ext_vector_type(8))) short bf16x8;
typedef __attribute__((ext_vector_type(4))) float f32x4;
typedef __attribute__((ext_vector_type(4))) unsigned short u16x4;

static __device__ __forceinline__ unsigned short f2bf(float f) {
    unsigned int u = __builtin_bit_cast(unsigned int, f);
    unsigned int r = (u + 0x7FFFu + ((u >> 16) & 1u)) >> 16;
    return (unsigned short)r;
}

// ---------------------------------------------------------------------------
// Kernel 1: router (double softmax) + 8 fused LoRA layers.
// 256 blocks x 1024 threads (16 waves -> 4/SIMD for latency hiding; the
// R4 8-wave version was load-latency bound at VALUBusy ~11%).
// 8 tokens/block, h fp32 in LDS; runs ALONE (R3 L2-thrash lesson).
// ---------------------------------------------------------------------------
__global__ __launch_bounds__(1024, 4) void fused_layers(
    const float* __restrict__ h_in,
    const float* __restrict__ router_w,
    const float* __restrict__ router_b,
    const float* __restrict__ expert_B,   // [E][L][R][H]
    const float* __restrict__ expert_A,   // [E][L][H][R]
    const float* __restrict__ deep_B,     // [L][R][H]
    const float* __restrict__ deep_A,     // [L][H][R]
    float* __restrict__ router_logits,
    unsigned short* __restrict__ h_out)
{
    __shared__ float h_lds[T8][HD];       // 128 KB
    __shared__ float zw_lds[T8][32];
    __shared__ float probs_lds[T8][EE];
    __shared__ float psum_lds[T8];
    __shared__ float red[16][T8][4];
    __shared__ float low_lds[T8][4];

    const int tid  = threadIdx.x;
    const int lane = tid & 63;
    const int wv   = tid >> 6;            // 0..15
    const int t0   = blockIdx.x * T8;

    // ---- load h tile: one 1024-float4 pass per token row
    for (int t = 0; t < T8; ++t)
        ((float4*)h_lds[t])[tid] = ((const float4*)(h_in + (size_t)(t0 + t) * HD))[tid];
    __syncthreads();

    // ---- router: waves 0-7, one token each
    if (wv < T8) {
        float racc[EE];
        #pragma unroll
        for (int e = 0; e < EE; ++e) racc[e] = 0.f;
        const float4* h4 = (const float4*)h_lds[wv];
        for (int k4 = 0; k4 < HD / 256; ++k4) {
            int idx = lane + k4 * 64;
            float4 hv = h4[idx];
            #pragma unroll
            for (int e = 0; e < EE; ++e) {
                float4 w4 = ((const float4*)(router_w + e * HD))[idx];
                racc[e] += w4.x * hv.x + w4.y * hv.y + w4.z * hv.z + w4.w * hv.w;
            }
        }
        #pragma unroll
        for (int e = 0; e < EE; ++e)
            for (int m = 1; m < 64; m <<= 1) racc[e] += __shfl_xor(racc[e], m);
        if (lane == 0) {
            float lg[EE], mx = -1e30f;
            #pragma unroll
            for (int e = 0; e < EE; ++e) { lg[e] = racc[e] + router_b[e]; mx = fmaxf(mx, lg[e]); }
            float s = 0.f;
            #pragma unroll
            for (int e = 0; e < EE; ++e) { lg[e] = expf(lg[e] - mx); s += lg[e]; }
            float inv = 1.f / s;
            float p1[EE], mx2 = -1e30f;
            #pragma unroll
            for (int e = 0; e < EE; ++e) { p1[e] = lg[e] * inv; mx2 = fmaxf(mx2, p1[e]); }
            float s2 = 0.f, q2[EE];
            #pragma unroll
            for (int e = 0; e < EE; ++e) { q2[e] = expf(p1[e] - mx2); s2 += q2[e]; }
            float inv2 = 1.f / s2, ps = 0.f;
            #pragma unroll
            for (int e = 0; e < EE; ++e) {
                float p2 = q2[e] * inv2;
                probs_lds[wv][e] = p2;
                ps += p2;
                router_logits[(size_t)(t0 + wv) * EE + e] = p1[e];
            }
            psum_lds[wv] = ps;
        }
    }
    __syncthreads();

    for (int li = 0; li < LL; ++li) {
        // ---- Z phase: wave wv owns er pairs wv*2+j (j<2), all 8 tokens
        {
            float zacc[2][T8] = {};
            const float4* bp4[2];
            #pragma unroll
            for (int j = 0; j < 2; ++j) {
                int er = wv * 2 + j;
                int e = er >> 2, r = er & 3;
                bp4[j] = (const float4*)(expert_B + (size_t)((e * LL + li) * RR + r) * HD);
            }
            for (int k4 = 0; k4 < HD / 256; ++k4) {
                int idx = lane + k4 * 64;
                float4 hv[T8];
                #pragma unroll
                for (int t = 0; t < T8; ++t) hv[t] = ((const float4*)h_lds[t])[idx];
                #pragma unroll
                for (int j = 0; j < 2; ++j) {
                    float4 w4 = bp4[j][idx];
                    #pragma unroll
                    for (int t = 0; t < T8; ++t)
                        zacc[j][t] += w4.x * hv[t].x + w4.y * hv[t].y +
                                      w4.z * hv[t].z + w4.w * hv[t].w;
                }
            }
            #pragma unroll
            for (int j = 0; j < 2; ++j)
                #pragma unroll
                for (int t = 0; t < T8; ++t) {
                    float v = zacc[j][t];
                    for (int m = 1; m < 64; m <<= 1) v += __shfl_xor(v, m);
                    zacc[j][t] = v;
                }
            if (lane == 0) {
                #pragma unroll
                for (int j = 0; j < 2; ++j) {
                    int er = wv * 2 + j;
                    #pragma unroll
                    for (int t = 0; t < T8; ++t)
                        zw_lds[t][er] = zacc[j][t] * probs_lds[t][er >> 2];
                }
            }
        }
        __syncthreads();

        // ---- delta phase: wave owns h-positions [wv*256, wv*256+256), 4/lane
        float dacc[T8][4] = {};
        const int pbase = wv * 256 + lane;
        for (int e = 0; e < EE; ++e) {
            float zwt[T8][4];
            #pragma unroll
            for (int t = 0; t < T8; ++t)
                #pragma unroll
                for (int r = 0; r < RR; ++r) zwt[t][r] = zw_lds[t][e * 4 + r];
            const float4* ap = (const float4*)expert_A + (size_t)(e * LL + li) * HD;
            #pragma unroll
            for (int it = 0; it < 4; ++it) {
                float4 a4 = ap[pbase + it * 64];
                #pragma unroll
                for (int t = 0; t < T8; ++t)
                    dacc[t][it] += zwt[t][0] * a4.x + zwt[t][1] * a4.y +
                                   zwt[t][2] * a4.z + zwt[t][3] * a4.w;
            }
        }

        // ---- combined = h*psum + delta; deep-B low partials
        float lowacc[T8][4] = {};
        float psv[T8];
        #pragma unroll
        for (int t = 0; t < T8; ++t) psv[t] = psum_lds[t];
        const float* dbp = deep_B + (size_t)li * (RR * HD);
        #pragma unroll
        for (int it = 0; it < 4; ++it) {
            int pos = pbase + it * 64;
            float db0 = dbp[pos], db1 = dbp[HD + pos], db2 = dbp[2 * HD + pos], db3 = dbp[3 * HD + pos];
            #pragma unroll
            for (int t = 0; t < T8; ++t) {
                float c = h_lds[t][pos] * psv[t] + dacc[t][it];
                h_lds[t][pos] = c;
                lowacc[t][0] += c * db0; lowacc[t][1] += c * db1;
                lowacc[t][2] += c * db2; lowacc[t][3] += c * db3;
            }
        }
        #pragma unroll
        for (int t = 0; t < T8; ++t)
            #pragma unroll
            for (int r = 0; r < RR; ++r) {
                float v = lowacc[t][r];
                for (int m = 1; m < 64; m <<= 1) v += __shfl_xor(v, m);
                lowacc[t][r] = v;
            }
        if (lane == 0) {
            #pragma unroll
            for (int t = 0; t < T8; ++t)
                #pragma unroll
                for (int r = 0; r < RR; ++r) red[wv][t][r] = lowacc[t][r];
        }
        __syncthreads();
        if (tid < 32) {
            int t = tid >> 2, r = tid & 3;
            float s = 0.f;
            #pragma unroll
            for (int w = 0; w < 16; ++w) s += red[w][t][r];
            low_lds[t][r] = s;
        }
        __syncthreads();

        // ---- up phase: h += low @ deep_A^T
        {
            float lw[T8][4];
            #pragma unroll
            for (int t = 0; t < T8; ++t)
                #pragma unroll
                for (int r = 0; r < RR; ++r) lw[t][r] = low_lds[t][r];
            const float4* dap = (const float4*)deep_A + (size_t)li * HD;
            #pragma unroll
            for (int it = 0; it < 4; ++it) {
                int pos = pbase + it * 64;
                float4 a4 = dap[pos];
                #pragma unroll
                for (int t = 0; t < T8; ++t)
                    h_lds[t][pos] += lw[t][0] * a4.x + lw[t][1] * a4.y +
                                     lw[t][2] * a4.z + lw[t][3] * a4.w;
            }
        }
        __syncthreads();
    }

    // ---- epilogue: h -> bf16 (one 1024-ushort4 pass per token row)
    for (int t = 0; t < T8; ++t) {
        float4 v = ((const float4*)h_lds[t])[tid];
        ushort4 o;
        o.x = f2bf(v.x); o.y = f2bf(v.y); o.z = f2bf(v.z); o.w = f2bf(v.w);
        ((ushort4*)(h_out + (size_t)(t0 + t) * HD))[tid] = o;
    }
}

// ---------------------------------------------------------------------------
// Kernel 2: lm_head_w fp32 -> bf16, nontemporal (read-once / write-once).
// Uses native ext_vector types (HIP_vector_type rejected by the builtin).
// ---------------------------------------------------------------------------
__global__ __launch_bounds__(256) void cvt_kernel(const f32x4* __restrict__ in,
                                                  u16x4* __restrict__ out, int n4)
{
    int i = blockIdx.x * 256 + threadIdx.x;
    int stride = gridDim.x * 256;
    for (; i < n4; i += stride) {
        f32x4 v = __builtin_nontemporal_load(&in[i]);
        u16x4 o;
        o.x = f2bf(v.x); o.y = f2bf(v.y); o.z = f2bf(v.z); o.w = f2bf(v.w);
        __builtin_nontemporal_store(o, &out[i]);
    }
}

// ---------------------------------------------------------------------------
// Kernel 3: 256x256 8-phase bf16 GEMM — R4-EXACT revert (known 518 us).
// Phase read balance: P0: 8 A | P1: 4 B | P2: 8 A | P3: 4 B(next, post-vmcnt).
// vmcnt ledger at P3: outstanding = B(kt+1):4 + A(kt+1):4 + B(kt+2):4 = 12;
// vmcnt(4) drains tile kt+1, leaves B(kt+2) in flight.
// ---------------------------------------------------------------------------
#define GLD(src, dst) __builtin_amdgcn_global_load_lds( \
    (const __attribute__((address_space(1))) unsigned int*)(src), \
    (__attribute__((address_space(3))) unsigned int*)(dst), 16, 0, 0)

#define STAGE(pp, matoff, bufv, hh, ktv) do { \
    char* db_ = smem + (bufv) * 65536 + (matoff) + (hh) * 16384 + wv * 1024; \
    GLD(pp[0] + (size_t)(hh) * (128ull * HD * 2) + (size_t)(ktv) * 128, db_); \
    GLD(pp[1] + (size_t)(hh) * (128ull * HD * 2) + (size_t)(ktv) * 128, db_ + 8192); \
} while (0)

#define LDSREAD(off) (*(const bf16x8*)(smem + (off)))

__global__ __launch_bounds__(512, 2) void lm_gemm256(
    const unsigned short* __restrict__ A,
    const unsigned short* __restrict__ Bw,
    float* __restrict__ C)
{
    __shared__ __attribute__((aligned(128))) char smem[131072];

    const int bid = blockIdx.x;
    const int swz = (bid & 7) * 125 + (bid >> 3);
    const int bm = swz & 7;
    const int bn = swz >> 3;

    const int tid  = threadIdx.x;
    const int lane = tid & 63;
    const int wv   = tid >> 6;
    const int wr   = wv >> 2;
    const int wc   = wv & 3;

    const char* pA[2];
    const char* pB[2];
    #pragma unroll
    for (int q = 0; q < 2; ++q) {
        int off = (q * 512 + tid) * 16;
        int p = off ^ (((off >> 9) & 1) << 5);
        int st = p >> 10;
        int r  = (st >> 1) * 16 + ((p >> 6) & 15);
        int cb = (st & 1) * 64 + (p & 63);
        pA[q] = (const char*)(A  + (size_t)(bm * 256 + r) * HD) + cb;
        pB[q] = (const char*)(Bw + (size_t)(bn * 256 + r) * HD) + cb;
    }

    const int xlane = ((lane >> 3) & 1) << 5;
    const int abase = ((wr * 8) << 11) + ((lane & 15) << 6) + ((lane >> 4) << 4);
    const int bbase = 32768 + ((wc * 4) << 11) + ((lane & 15) << 6) + ((lane >> 4) << 4);

    f32x4 acc[8][4] = {};
    bf16x8 aF[4][2], bF0[2][2][2], bF1[2][2];

    STAGE(pB, 32768, 0, 0, 0);
    STAGE(pB, 32768, 0, 1, 0);
    STAGE(pA, 0,     0, 0, 0);
    STAGE(pA, 0,     0, 1, 0);
    STAGE(pB, 32768, 1, 0, 1);
    STAGE(pB, 32768, 1, 1, 1);
    asm volatile("s_waitcnt vmcnt(4)" ::: "memory");
    __builtin_amdgcn_s_barrier();
    __builtin_amdgcn_sched_barrier(0);
    #pragma unroll
    for (int n = 0; n < 2; ++n)
        #pragma unroll
        for (int ks = 0; ks < 2; ++ks)
            bF0[0][n][ks] = LDSREAD(((bbase + (n << 11) + (ks << 10)) ^ xlane));

    #pragma unroll 2
    for (int kt = 0; kt < NKT; ++kt) {
        const int cur = kt & 1;
        const int oth = cur ^ 1;
        const int cb0 = cur << 16;

        // ---------------- PHASE 0 : (mh0, nh0)  [8 A reads]
        #pragma unroll
        for (int i = 0; i < 4; ++i)
            #pragma unroll
            for (int ks = 0; ks < 2; ++ks)
                aF[i][ks] = LDSREAD(cb0 + ((abase + (i << 11) + (ks << 10)) ^ xlane));
        if (kt + 1 < NKT) STAGE(pA, 0, oth, 0, kt + 1);
        __builtin_amdgcn_s_barrier();
        __builtin_amdgcn_sched_barrier(0);
        __builtin_amdgcn_s_setprio(1);
        #pragma unroll
        for (int ks = 0; ks < 2; ++ks)
            #pragma unroll
            for (int i = 0; i < 4; ++i)
                #pragma unroll
                for (int n = 0; n < 2; ++n)
                    acc[i][n] = __builtin_amdgcn_mfma_f32_16x16x32_bf16(
                        aF[i][ks], bF0[cur][n][ks], acc[i][n], 0, 0, 0);
        __builtin_amdgcn_s_setprio(0);
        __builtin_amdgcn_s_barrier();
        __builtin_amdgcn_sched_barrier(0);

        // ---------------- PHASE 1 : (mh0, nh1)  [4 B reads]
        #pragma unroll
        for (int n = 0; n < 2; ++n)
            #pragma unroll
            for (int ks = 0; ks < 2; ++ks)
                bF1[n][ks] = LDSREAD(cb0 + ((bbase + ((n + 2) << 11) + (ks << 10)) ^ xlane));
        if (kt + 1 < NKT) STAGE(pA, 0, oth, 1, kt + 1);
        __builtin_amdgcn_s_barrier();
        __builtin_amdgcn_sched_barrier(0);
        __builtin_amdgcn_s_setprio(1);
        #pragma unroll
        for (int ks = 0; ks < 2; ++ks)
            #pragma unroll
            for (int i = 0; i < 4; ++i)
                #pragma unroll
                for (int n = 0; n < 2; ++n)
                    acc[i][n + 2] = __builtin_amdgcn_mfma_f32_16x16x32_bf16(
                        aF[i][ks], bF1[n][ks], acc[i][n + 2], 0, 0, 0);
        __builtin_amdgcn_s_setprio(0);
        __builtin_amdgcn_s_barrier();
        __builtin_amdgcn_sched_barrier(0);

        // ---------------- PHASE 2 : (mh1, nh1)  [8 A reads]
        #pragma unroll
        for (int i = 0; i < 4; ++i)
            #pragma unroll
            for (int ks = 0; ks < 2; ++ks)
                aF[i][ks] = LDSREAD(cb0 + ((abase + ((i + 4) << 11) + (ks << 10)) ^ xlane));
        if (kt + 2 < NKT) STAGE(pB, 32768, cur, 0, kt + 2);
        __builtin_amdgcn_s_barrier();
        __builtin_amdgcn_sched_barrier(0);
        __builtin_amdgcn_s_setprio(1);
        #pragma unroll
        for (int ks = 0; ks < 2; ++ks)
            #pragma unroll
            for (int i = 0; i < 4; ++i)
                #pragma unroll
                for (int n = 0; n < 2; ++n)
                    acc[i + 4][n + 2] = __builtin_amdgcn_mfma_f32_16x16x32_bf16(
                        aF[i][ks], bF1[n][ks], acc[i + 4][n + 2], 0, 0, 0);
        __builtin_amdgcn_s_setprio(0);
        __builtin_amdgcn_s_barrier();
        __builtin_amdgcn_sched_barrier(0);

        // ---------------- PHASE 3 : (mh1, nh0)  [4 B(next) reads after barrier]
        if (kt + 2 < NKT) {
            STAGE(pB, 32768, cur, 1, kt + 2);
            asm volatile("s_waitcnt vmcnt(4)" ::: "memory");
        } else {
            asm volatile("s_waitcnt vmcnt(0)" ::: "memory");
        }
        __builtin_amdgcn_s_barrier();
        __builtin_amdgcn_sched_barrier(0);
        if (kt + 1 < NKT) {
            const int nb0 = oth << 16;
            #pragma unroll
            for (int n = 0; n < 2; ++n)
                #pragma unroll
                for (int ks = 0; ks < 2; ++ks)
                    bF0[oth][n][ks] = LDSREAD(nb0 + ((bbase + (n << 11) + (ks << 10)) ^ xlane));
        }
        __builtin_amdgcn_s_setprio(1);
        #pragma unroll
        for (int ks = 0; ks < 2; ++ks)
            #pragma unroll
            for (int i = 0; i < 4; ++i)
                #pragma unroll
                for (int n = 0; n < 2; ++n)
                    acc[i + 4][n] = __builtin_amdgcn_mfma_f32_16x16x32_bf16(
                        aF[i][ks], bF0[cur][n][ks], acc[i + 4][n], 0, 0, 0);
        __builtin_amdgcn_s_setprio(0);
        __builtin_amdgcn_s_barrier();
        __builtin_amdgcn_sched_barrier(0);
    }

    const int crow0 = bm * 256 + wr * 128 + ((lane >> 4) << 2);
    const int ccol0 = bn * 256 + wc * 64 + (lane & 15);
    #pragma unroll
    for (int fm = 0; fm < 8; ++fm)
        #pragma unroll
        for (int fn = 0; fn < 4; ++fn) {
            int row = crow0 + fm * 16;
            int col = ccol0 + fn * 16;
            #pragma unroll
            for (int j = 0; j < 4; ++j)
                C[(size_t)(row + j) * VV + col] = acc[fm][fn][j];
        }
}

// ---------------------------------------------------------------------------
extern "C" void kernel_launch(void* const* d_in, const int* in_sizes, int n_in,
                              void* d_out, int out_size, void* d_ws, size_t ws_size,
                              hipStream_t stream) {
    const float* h_in      = (const float*)d_in[0];
    const float* router_w  = (const float*)d_in[1];
    const float* router_b  = (const float*)d_in[2];
    const float* expert_B  = (const float*)d_in[3];
    const float* expert_A  = (const float*)d_in[4];
    const float* deep_B    = (const float*)d_in[5];
    const float* deep_A    = (const float*)d_in[6];
    const float* lm_head_w = (const float*)d_in[7];

    float* out = (float*)d_out;
    float* router_logits_out = out + (size_t)NTOK * VV;

    unsigned short* h_bf = (unsigned short*)d_ws;
    unsigned short* w_bf = (unsigned short*)((char*)d_ws + (size_t)NTOK * HD * 2);

    fused_layers<<<dim3(NTOK / T8), dim3(1024), 0, stream>>>(
        h_in, router_w, router_b, expert_B, expert_A, deep_B, deep_A,
        router_logits_out, h_bf);

    cvt_kernel<<<dim3(4096), dim3(256), 0, stream>>>(
        (const f32x4*)lm_head_w, (u16x4*)w_bf, VV * HD / 4);

    lm_gemm256<<<dim3((NTOK / 256) * (VV / 256)), dim3(512), 0, stream>>>(
        h_bf, w_bf, out);
}